// Round 7
// baseline (485.760 us; speedup 1.0000x reference)
//
#include <hip/hip_runtime.h>
#include <math.h>

#define B 2
#define S 256
#define H 768
#define L 50
#define E 512
#define W 10
#define SG 8
#define NSPAN 2515
#define KTOP 102
#define D3 2304
#define N6 6912

// workspace float offsets
#define OFF_GOUT ((size_t)0)         // 512*768
#define OFF_EMB  ((size_t)393216)    // 512*768
#define OFF_G    ((size_t)786432)    // 512*6912
#define OFF_TOKD ((size_t)4325376)   // 512*8
#define OFF_MENT ((size_t)4329472)   // 5120
#define OFF_SJ   ((size_t)4334592)   // 5120
#define OFF_SI   ((size_t)4339712)   // 5120
#define OFF_INT  ((size_t)4345344)   // int region (2048 floats reserved)
#define OFF_EMBT ((size_t)4347392)   // 768*512
#define OFF_W1T  ((size_t)4740608)   // 2304*2304  (ends 10049024 floats = 40.2 MB)

// ---------------------------------------------------------------- zero-init (replaces 2 memsets)
__global__ __launch_bounds__(256) void k_init(float* __restrict__ gout, float* __restrict__ ment) {
    int i = blockIdx.x * 256 + threadIdx.x;
    if (i < B * S * H) gout[i] = 0.f;
    if (i < B * NSPAN) ment[i] = 0.f;
}

// ---------------------------------------------------------------- edge grouping
__global__ __launch_bounds__(1024) void k_group(
    const int* __restrict__ esrc, const int* __restrict__ etgt,
    const int* __restrict__ elab, int* __restrict__ cnt,
    int* __restrict__ off, int* __restrict__ edges) {
    __shared__ int lcnt[L];
    __shared__ int loff[L];
    int t = threadIdx.x;  // t == global edge id, blockDim == B*E == 1024
    if (t < L) lcnt[t] = 0;
    __syncthreads();
    int lab = elab[t], src = esrc[t], tgt = etgt[t];
    bool valid = (lab >= 0) && (lab < L) && (src >= 0) && (src < S) && (tgt >= 0) && (tgt < S);
    int mypos = -1;
    if (valid) mypos = atomicAdd(&lcnt[lab], 1);
    __syncthreads();
    if (t == 0) {
        int acc = 0;
        for (int l = 0; l < L; l++) { loff[l] = acc; acc += lcnt[l]; }
    }
    __syncthreads();
    if (valid) edges[loff[lab] + mypos] = t;
    if (t < L) { cnt[t] = lcnt[t]; off[t] = loff[t]; }
}

// ---------------------------------------------------------------- generic 32x32 tiled transpose: out[C][R] = in[R][C]^T
__global__ __launch_bounds__(256) void k_trans(
    const float* __restrict__ in, float* __restrict__ out, int R, int C) {
    __shared__ float T[32][33];
    int c0 = blockIdx.x * 32, r0 = blockIdx.y * 32;
    int tid = threadIdx.x;
    int cc = tid & 31, r8 = tid >> 5;
#pragma unroll
    for (int i = 0; i < 4; i++) {
        int rr = r8 + 8 * i;
        T[rr][cc] = in[(size_t)(r0 + rr) * C + c0 + cc];
    }
    __syncthreads();
    int rr2 = tid & 31, c8 = tid >> 5;
#pragma unroll
    for (int i = 0; i < 4; i++) {
        int cc2 = c8 + 8 * i;
        out[(size_t)(c0 + cc2) * R + r0 + rr2] = T[rr2][cc2];
    }
}

// ---------------------------------------------------------------- GCN as per-label GEMM tiles
#define GK 384
__global__ __launch_bounds__(256) void k_gcn(
    const float* __restrict__ hidden, const float* __restrict__ gcnW,
    const float* __restrict__ gcnb, const int* __restrict__ cnt,
    const int* __restrict__ off, const int* __restrict__ edges,
    const int* __restrict__ esrc, const int* __restrict__ etgt,
    float* __restrict__ gout) {
    int l = blockIdx.y;
    int n = cnt[l];
    if (n == 0) return;
    int row0 = blockIdx.x * 64;
    int kbase = blockIdx.z * GK;
    __shared__ float Ws[32][68];   // [k][row], padded
    __shared__ float Xs[32][34];   // [k][edge]
    __shared__ int srow[32];
    __shared__ int trow[32];
    int tid = threadIdx.x;
    int tx = tid & 15, ty = tid >> 4;
    // X staging coords: 32 e x 8 float4-chunks
    int ex = tid >> 3, k4 = (tid & 7) * 4;
    int o = off[l];
    for (int e0 = 0; e0 < n; e0 += 32) {
        int nv = min(32, n - e0);
        if (tid < 32) {
            int sr = 0, tr = 0;
            if (tid < nv) {
                int g = edges[o + e0 + tid];
                int bb = g / E;
                sr = (bb * S + esrc[g]) * H;
                tr = (bb * S + etgt[g]) * H;
            }
            srow[tid] = sr;
            trow[tid] = tr;
        }
        __syncthreads();
        float acc[4][2];
#pragma unroll
        for (int r = 0; r < 4; r++) { acc[r][0] = 0.f; acc[r][1] = 0.f; }
        for (int kc = 0; kc < GK; kc += 32) {
            int k0 = kbase + kc;
#pragma unroll
            for (int j = 0; j < 2; j++) {
                int f = tid + 256 * j;
                int r = f >> 3, kq = (f & 7) * 4;
                float4 v = *(const float4*)(gcnW + ((size_t)l * H + row0 + r) * H + k0 + kq);
                Ws[kq + 0][r] = v.x; Ws[kq + 1][r] = v.y;
                Ws[kq + 2][r] = v.z; Ws[kq + 3][r] = v.w;
            }
            {
                float4 xv = *(const float4*)(hidden + srow[ex] + k0 + k4);
                Xs[k4 + 0][ex] = xv.x; Xs[k4 + 1][ex] = xv.y;
                Xs[k4 + 2][ex] = xv.z; Xs[k4 + 3][ex] = xv.w;
            }
            __syncthreads();
#pragma unroll
            for (int k = 0; k < 32; k++) {
                float4 a = *(const float4*)&Ws[k][ty * 4];
                float2 x2 = *(const float2*)&Xs[k][tx * 2];
                acc[0][0] = fmaf(a.x, x2.x, acc[0][0]);
                acc[1][0] = fmaf(a.y, x2.x, acc[1][0]);
                acc[2][0] = fmaf(a.z, x2.x, acc[2][0]);
                acc[3][0] = fmaf(a.w, x2.x, acc[3][0]);
                acc[0][1] = fmaf(a.x, x2.y, acc[0][1]);
                acc[1][1] = fmaf(a.y, x2.y, acc[1][1]);
                acc[2][1] = fmaf(a.z, x2.y, acc[2][1]);
                acc[3][1] = fmaf(a.w, x2.y, acc[3][1]);
            }
            __syncthreads();
        }
        const float* bp = gcnb + l * H + row0 + ty * 4;
        bool addb = (blockIdx.z == 0);
#pragma unroll
        for (int e = 0; e < 2; e++) {
            int ei = tx * 2 + e;
            if (ei < nv) {
                int base = trow[ei] + row0 + ty * 4;
#pragma unroll
                for (int r = 0; r < 4; r++) {
                    float v = acc[r][e];
                    if (addb) v += bp[r];
                    atomicAdd(&gout[base + r], v);
                }
            }
        }
        __syncthreads();
    }
}

// ---------------------------------------------------------------- emb = hidden + relu(gout), plus per-token dots
__global__ __launch_bounds__(256) void k_embdots(
    const float* __restrict__ hidden, const float* __restrict__ gout,
    const float* __restrict__ attnw, const float* __restrict__ antw,
    float* __restrict__ emb, float* __restrict__ tokd) {
    int wave = threadIdx.x >> 6, lane = threadIdx.x & 63;
    int tok = blockIdx.x * 4 + wave;
    const float* hp = hidden + (size_t)tok * H;
    const float* gp = gout + (size_t)tok * H;
    float* ep = emb + (size_t)tok * H;
    float p[7] = {0, 0, 0, 0, 0, 0, 0};
#pragma unroll
    for (int m = 0; m < 12; m++) {
        int k = lane + 64 * m;
        float e = hp[k] + fmaxf(gp[k], 0.f);
        ep[k] = e;
        p[0] = fmaf(attnw[k], e, p[0]);
#pragma unroll
        for (int q = 0; q < 6; q++) p[1 + q] = fmaf(antw[q * H + k], e, p[1 + q]);
    }
#pragma unroll
    for (int q = 0; q < 7; q++) {
        float v = p[q];
#pragma unroll
        for (int d = 32; d; d >>= 1) v += __shfl_down(v, d);
        p[q] = v;
    }
    if (lane == 0) {
        float* o = tokd + (size_t)tok * 8;
#pragma unroll
        for (int q = 0; q < 7; q++) o[q] = p[q];
    }
}

// ---------------------------------------------------------------- G = emb @ W1-blocks^T via pre-transposed inputs
// R5 lesson: NAMED scalar accs/prefetch only (arrays → scratch demotion).
// R7: split into 3 launches (one per 2304-col block) for profile visibility;
// f32 VALU GEMM is at its ~50%-issue structural plateau (R5≈R6≈89 µs).
__global__ __launch_bounds__(256, 4) void k_gemm(
    const float* __restrict__ embT, const float* __restrict__ W1T,
    float* __restrict__ G, int n_base) {
    __shared__ float As[32][68];
    __shared__ float Bs[32][68];
    int n0 = n_base + blockIdx.x * 64;
    int m0 = blockIdx.y * 64;
    int blk = n0 / D3;
    int e0 = n0 - blk * D3;
    int tid = threadIdx.x;
    int tx = tid & 15, ty = tid >> 4;
    const float* Ap = embT + m0;                          // embT[k][m0+..], row stride 512
    const float* Bp = W1T + (size_t)(blk * H) * D3 + e0;  // W1T[blk*768+k][e0+..], row stride D3
    int r0 = tid >> 4, q0 = (tid & 15) * 4;
    int r1 = (tid + 256) >> 4, q1 = ((tid + 256) & 15) * 4;
    float4 pa0 = *(const float4*)(Ap + (size_t)r0 * 512 + q0);
    float4 pa1 = *(const float4*)(Ap + (size_t)r1 * 512 + q1);
    float4 pb0 = *(const float4*)(Bp + (size_t)r0 * D3 + q0);
    float4 pb1 = *(const float4*)(Bp + (size_t)r1 * D3 + q1);
    float c00 = 0.f, c01 = 0.f, c02 = 0.f, c03 = 0.f;
    float c10 = 0.f, c11 = 0.f, c12 = 0.f, c13 = 0.f;
    float c20 = 0.f, c21 = 0.f, c22 = 0.f, c23 = 0.f;
    float c30 = 0.f, c31 = 0.f, c32 = 0.f, c33 = 0.f;
    for (int kt = 0; kt < H; kt += 32) {
        *(float4*)&As[r0][q0] = pa0;
        *(float4*)&As[r1][q1] = pa1;
        *(float4*)&Bs[r0][q0] = pb0;
        *(float4*)&Bs[r1][q1] = pb1;
        __syncthreads();
        if (kt + 32 < H) {
            const float* Apn = Ap + (size_t)(kt + 32) * 512;
            const float* Bpn = Bp + (size_t)(kt + 32) * D3;
            pa0 = *(const float4*)(Apn + (size_t)r0 * 512 + q0);
            pa1 = *(const float4*)(Apn + (size_t)r1 * 512 + q1);
            pb0 = *(const float4*)(Bpn + (size_t)r0 * D3 + q0);
            pb1 = *(const float4*)(Bpn + (size_t)r1 * D3 + q1);
        }
#pragma unroll
        for (int k = 0; k < 32; k++) {
            float4 av = *(const float4*)&As[k][ty * 4];
            float4 bv = *(const float4*)&Bs[k][tx * 4];
            c00 = fmaf(av.x, bv.x, c00); c01 = fmaf(av.x, bv.y, c01);
            c02 = fmaf(av.x, bv.z, c02); c03 = fmaf(av.x, bv.w, c03);
            c10 = fmaf(av.y, bv.x, c10); c11 = fmaf(av.y, bv.y, c11);
            c12 = fmaf(av.y, bv.z, c12); c13 = fmaf(av.y, bv.w, c13);
            c20 = fmaf(av.z, bv.x, c20); c21 = fmaf(av.z, bv.y, c21);
            c22 = fmaf(av.z, bv.z, c22); c23 = fmaf(av.z, bv.w, c23);
            c30 = fmaf(av.w, bv.x, c30); c31 = fmaf(av.w, bv.y, c31);
            c32 = fmaf(av.w, bv.z, c32); c33 = fmaf(av.w, bv.w, c33);
        }
        __syncthreads();
    }
    float* g0 = G + (size_t)(m0 + ty * 4 + 0) * N6 + n0 + tx * 4;
    float* g1 = G + (size_t)(m0 + ty * 4 + 1) * N6 + n0 + tx * 4;
    float* g2 = G + (size_t)(m0 + ty * 4 + 2) * N6 + n0 + tx * 4;
    float* g3 = G + (size_t)(m0 + ty * 4 + 3) * N6 + n0 + tx * 4;
    *(float4*)g0 = make_float4(c00, c01, c02, c03);
    *(float4*)g1 = make_float4(c10, c11, c12, c13);
    *(float4*)g2 = make_float4(c20, c21, c22, c23);
    *(float4*)g3 = make_float4(c30, c31, c32, c33);
}

// ---------------------------------------------------------------- span kernel, start-grouped (SG starts/block)
// R7: bm/cj rows staged once in LDS per start-group -> G traffic 99->25 MB,
// blocks 4608->576. ms_b2 / attn_b dropped (constant shifts).
__global__ __launch_bounds__(256) void k_span(
    const float* __restrict__ G, const float* __restrict__ tokd,
    const float* __restrict__ b1, const float* __restrict__ w2,
    float* __restrict__ ment, float* __restrict__ sjA, float* __restrict__ siA) {
    int ec = blockIdx.x;
    int s0 = blockIdx.y * SG;
    int b = blockIdx.z;
    int tid = threadIdx.x;
    __shared__ float aw[SG][W][W + 1];
    __shared__ float bmS[SG + W - 1][257];
    __shared__ float cjS[SG + W - 1][257];
    const float* td = tokd + (size_t)(b * S) * 8;
    const float* Gb = G + (size_t)(b * S) * N6;
    int e = ec * 256 + tid;
    // stage bm/cj rows s0..s0+16 for this e-chunk
#pragma unroll
    for (int r = 0; r < SG + W - 1; r++) {
        int row = s0 + r; if (row > S - 1) row = S - 1;
        bmS[r][tid] = Gb[(size_t)row * N6 + D3 + e];
        cjS[r][tid] = Gb[(size_t)row * N6 + 2 * D3 + e];
    }
    // attention weights (+ sj/si on ec==0)
    if (tid < SG * W) {
        int sg = tid / W, w = tid % W;
        int start = s0 + sg;
        int nw = min(W, S - start);
        if (w < nw) {
            float sc[W];
            float mx = -3.0e38f;
            for (int j = 0; j <= w; j++) { sc[j] = td[(start + j) * 8]; mx = fmaxf(mx, sc[j]); }
            float sum = 0.f;
            for (int j = 0; j <= w; j++) { float ev = expf(sc[j] - mx); aw[sg][w][j] = ev; sum += ev; }
            float inv = 1.f / sum;
            for (int j = 0; j <= w; j++) aw[sg][w][j] *= inv;
            if (ec == 0) {
                int tail = S - start;
                int base = (start <= S - W) ? start * W
                         : (S - W + 1) * W + ((W - 1) * W / 2 - tail * (tail + 1) / 2);
                float sj = td[start * 8 + 1] + td[(start + w) * 8 + 2];
                float si = td[start * 8 + 4] + td[(start + w) * 8 + 5];
                for (int j = 0; j <= w; j++) {
                    sj = fmaf(aw[sg][w][j], td[(start + j) * 8 + 3], sj);
                    si = fmaf(aw[sg][w][j], td[(start + j) * 8 + 6], si);
                }
                sjA[b * NSPAN + base + w] = sj;
                siA[b * NSPAN + base + w] = si;
            }
        }
    }
    __syncthreads();
    float w2e = w2[e];
    int lane = tid & 63;
    for (int sg = 0; sg < SG; sg++) {
        int start = s0 + sg;
        int nw = min(W, S - start);
        int tail = S - start;
        int base = (start <= S - W) ? start * W
                 : (S - W + 1) * W + ((W - 1) * W / 2 - tail * (tail + 1) / 2);
        float a = Gb[(size_t)start * N6 + e] + b1[e];
        float cj[W], bm[W];
#pragma unroll
        for (int j = 0; j < W; j++) {
            if (j < nw) { cj[j] = cjS[sg + j][tid]; bm[j] = bmS[sg + j][tid]; }
            else { cj[j] = 0.f; bm[j] = 0.f; }
        }
#pragma unroll
        for (int w = 0; w < W; w++) {
            float v = 0.f;
            if (w < nw) {
                float pre = a + bm[w];
#pragma unroll
                for (int j = 0; j <= w; j++) pre = fmaf(aw[sg][w][j], cj[j], pre);
                v = fmaxf(pre, 0.f) * w2e;
            }
#pragma unroll
            for (int d = 32; d; d >>= 1) v += __shfl_down(v, d);
            if (lane == 0 && w < nw) atomicAdd(&ment[b * NSPAN + base + w], v);
        }
    }
}

// ---------------------------------------------------------------- fused top-k (radix select) + antecedent log-softmax
__global__ __launch_bounds__(256) void k_topkant(
    const float* __restrict__ ment, const float* __restrict__ sjA,
    const float* __restrict__ siA, const float* __restrict__ antb,
    float* __restrict__ out) {
    __shared__ unsigned int uv[NSPAN];
    __shared__ int hist[4][256];
    __shared__ int suf[256];
    __shared__ int cand_i[160];
    __shared__ unsigned int cand_u[160];
    __shared__ int ncand;
    __shared__ unsigned int s_prefix;
    __shared__ int s_kk;
    __shared__ float selj[KTOP];
    __shared__ float seli[KTOP];
    int b = blockIdx.x, tid = threadIdx.x;
    int wave = tid >> 6, lane = tid & 63;
    for (int n = tid; n < NSPAN; n += 256) {
        unsigned int u = __float_as_uint(ment[b * NSPAN + n]);
        uv[n] = (u & 0x80000000u) ? ~u : (u | 0x80000000u);
    }
    if (tid == 0) { s_prefix = 0u; s_kk = KTOP; ncand = 0; }
    __syncthreads();
    for (int pass = 3; pass >= 0; pass--) {
        int shift = pass * 8;
#pragma unroll
        for (int q = 0; q < 4; q++) hist[q][tid] = 0;
        __syncthreads();
        unsigned int pref = s_prefix;
        unsigned int pmask = (pass == 3) ? 0u : (0xFFFFFFFFu << (shift + 8));
        for (int n = tid; n < NSPAN; n += 256) {
            unsigned int u = uv[n];
            if ((u & pmask) == pref) atomicAdd(&hist[wave][(u >> shift) & 255], 1);
        }
        __syncthreads();
        suf[tid] = hist[0][tid] + hist[1][tid] + hist[2][tid] + hist[3][tid];
        __syncthreads();
        for (int d2 = 1; d2 < 256; d2 <<= 1) {
            int y = suf[tid] + ((tid + d2 < 256) ? suf[tid + d2] : 0);
            __syncthreads();
            suf[tid] = y;
            __syncthreads();
        }
        int kk = s_kk;
        __syncthreads();
        if (suf[tid] >= kk && (tid == 255 || suf[tid + 1] < kk)) {
            s_prefix = pref | ((unsigned int)tid << shift);
            s_kk = kk - ((tid == 255) ? 0 : suf[tid + 1]);
        }
        __syncthreads();
    }
    unsigned int uk = s_prefix;   // exact k-th largest key
    for (int n = tid; n < NSPAN; n += 256) {
        if (uv[n] >= uk) {
            int p = atomicAdd(&ncand, 1);
            if (p < 160) { cand_i[p] = n; cand_u[p] = uv[n]; }
        }
    }
    __syncthreads();
    int nc = min(ncand, 160);
    for (int c = tid; c < nc; c += 256) {
        unsigned int u = cand_u[c];
        int idx = cand_i[c];
        int rank = 0;
        for (int d = 0; d < nc; d++) {
            unsigned int ud = cand_u[d];
            if (ud > u || (ud == u && cand_i[d] < idx)) rank++;
        }
        if (rank < KTOP) {
            selj[rank] = sjA[b * NSPAN + idx];
            seli[rank] = siA[b * NSPAN + idx];
        }
    }
    __syncthreads();
    float ab = antb[0];
    for (int i = wave; i < KTOP; i += 4) {
        float si = seli[i];
        float v0, v1;
        if (lane == 0) v0 = 0.f;
        else {
            int j = lane - 1;
            v0 = (j >= i) ? -1e10f : (selj[j] + si + ab);
        }
        int c1 = lane + 64;
        bool v1ok = (c1 <= KTOP);
        if (v1ok) {
            int j = c1 - 1;
            v1 = (j >= i) ? -1e10f : (selj[j] + si + ab);
        } else v1 = -3.0e38f;
        float mx = fmaxf(v0, v1);
#pragma unroll
        for (int d = 32; d; d >>= 1) mx = fmaxf(mx, __shfl_down(mx, d));
        mx = __shfl(mx, 0);
        float e0 = expf(v0 - mx);
        float e1 = v1ok ? expf(v1 - mx) : 0.f;
        float sm = e0 + e1;
#pragma unroll
        for (int d = 32; d; d >>= 1) sm += __shfl_down(sm, d);
        sm = __shfl(sm, 0);
        float* op = out + (size_t)(b * KTOP + i) * (KTOP + 1);
        op[lane] = logf(e0 / sm + 1e-10f);
        if (v1ok) op[c1] = logf(e1 / sm + 1e-10f);
    }
}

extern "C" void kernel_launch(void* const* d_in, const int* in_sizes, int n_in,
                              void* d_out, int out_size, void* d_ws, size_t ws_size,
                              hipStream_t stream) {
    (void)in_sizes; (void)n_in; (void)out_size; (void)ws_size;
    const float* hidden = (const float*)d_in[0];
    const int*   esrc   = (const int*)d_in[2];
    const int*   etgt   = (const int*)d_in[3];
    const int*   elab   = (const int*)d_in[4];
    const float* gcnW   = (const float*)d_in[5];
    const float* gcnb   = (const float*)d_in[6];
    const float* attnw  = (const float*)d_in[7];
    const float* msW1   = (const float*)d_in[9];
    const float* msb1   = (const float*)d_in[10];
    const float* msw2   = (const float*)d_in[11];
    const float* antw   = (const float*)d_in[13];
    const float* antb   = (const float*)d_in[14];
    float* out = (float*)d_out;

    float* wsf  = (float*)d_ws;
    float* gout = wsf + OFF_GOUT;
    float* emb  = wsf + OFF_EMB;
    float* G    = wsf + OFF_G;
    float* tokd = wsf + OFF_TOKD;
    float* ment = wsf + OFF_MENT;
    float* sjA  = wsf + OFF_SJ;
    float* siA  = wsf + OFF_SI;
    float* embT = wsf + OFF_EMBT;
    float* W1T  = wsf + OFF_W1T;
    int* wsi   = (int*)(wsf + OFF_INT);
    int* cnt   = wsi;
    int* off   = wsi + 64;
    int* edges = wsi + 128;

    k_init<<<(B * S * H + 255) / 256, 256, 0, stream>>>(gout, ment);
    k_group<<<1, B * E, 0, stream>>>(esrc, etgt, elab, cnt, off, edges);
    k_trans<<<dim3(D3 / 32, D3 / 32), 256, 0, stream>>>(msW1, W1T, D3, D3);
    k_gcn<<<dim3(12, L, 2), 256, 0, stream>>>(hidden, gcnW, gcnb, cnt, off, edges, esrc, etgt, gout);
    k_embdots<<<B * S / 4, 256, 0, stream>>>(hidden, gout, attnw, antw, emb, tokd);
    k_trans<<<dim3(H / 32, (B * S) / 32), 256, 0, stream>>>(emb, embT, B * S, H);
    k_gemm<<<dim3(D3 / 64, (B * S) / 64), 256, 0, stream>>>(embT, W1T, G, 0);
    k_gemm<<<dim3(D3 / 64, (B * S) / 64), 256, 0, stream>>>(embT, W1T, G, D3);
    k_gemm<<<dim3(D3 / 64, (B * S) / 64), 256, 0, stream>>>(embT, W1T, G, 2 * D3);
    k_span<<<dim3(D3 / 256, S / SG, B), 256, 0, stream>>>(G, tokd, msb1, msw2, ment, sjA, siA);
    k_topkant<<<B, 256, 0, stream>>>(ment, sjA, siA, antb, out);
}